// Round 7
// baseline (220.250 us; speedup 1.0000x reference)
//
#include <hip/hip_runtime.h>

// GCN 2-layer encoder on gfx950.
// R7: (a) dynamic within-block walk balancing in both aggregate kernels
//     (LDS node counter, lane0 grab + shfl broadcast) — kills Poisson
//     tail-divergence (wave time max->mean); (b) scan_buckets folded into
//     p2_csr (in-block 512-slot scan of bucket counts; -1 dispatch).
// Pipeline: memset(1.5KB) -> p1_bin -> p2_csr -> gemm1(bf16 h1)
//           -> agg1_gemm2(bf16 h2) -> agg2 -> d_out (fp32).

constexpr int CAP = 8192;   // per-bucket staging cap; E/NB ~ 4092
constexpr int NBMAX = 512;  // NB = 391 for N = 100000 (must be <= 512)

__device__ inline unsigned short f2bf(float f) {  // RNE f32->bf16 (finite inputs)
    unsigned u = __float_as_uint(f);
    u += 0x7fff + ((u >> 16) & 1);
    return (unsigned short)(u >> 16);
}
__device__ inline float bflo(unsigned u) { return __uint_as_float(u << 16); }
__device__ inline float bfhi(unsigned u) { return __uint_as_float(u & 0xffff0000u); }

__global__ __launch_bounds__(256) void p1_bin(const int* __restrict__ src,
                                              const int* __restrict__ dst,
                                              int* __restrict__ bucketCursor,
                                              unsigned* __restrict__ staging, int E, int NB) {
    __shared__ int cnt[NBMAX];
    __shared__ int cur[NBMAX];
    int tid = threadIdx.x;
    for (int i = tid; i < NB; i += 256) cnt[i] = 0;
    __syncthreads();
    int e0 = blockIdx.x * 4096;
#pragma unroll
    for (int k = 0; k < 16; ++k) {
        int e = e0 + k * 256 + tid;
        if (e < E) atomicAdd(&cnt[dst[e] >> 8], 1);  // LDS atomic
    }
    __syncthreads();
    for (int i = tid; i < NB; i += 256) {
        int c = cnt[i];
        cur[i] = c ? atomicAdd(&bucketCursor[i], c) : 0;  // 1 global atomic/(block,bucket)
    }
    __syncthreads();
#pragma unroll
    for (int k = 0; k < 16; ++k) {
        int e = e0 + k * 256 + tid;
        if (e < E) {
            int d = dst[e];
            int b = d >> 8;
            int slot = atomicAdd(&cur[b], 1);  // LDS atomic; runs contiguous per bucket
            staging[(size_t)b * CAP + slot] = ((unsigned)src[e] << 8) | (unsigned)(d & 255);
        }
    }
}

// One block per bucket. In-block scan of all bucket counts replaces the old
// scan_buckets dispatch; then local deg/scan/cursor in LDS; emit rp, col, dinv.
__global__ __launch_bounds__(256) void p2_csr(const unsigned* __restrict__ staging,
                                              const int* __restrict__ bucketCursor,
                                              int* __restrict__ rp, int* __restrict__ col,
                                              float* __restrict__ dinv, int N, int E, int NB) {
    __shared__ int sb[NBMAX];
    __shared__ int deg[256];
    __shared__ int scn[256];
    __shared__ int cur[256];
    int b = blockIdx.x;
    int tid = threadIdx.x;
    int i1 = tid, i2 = tid + 256;
    sb[i1] = (i1 < NB) ? bucketCursor[i1] : 0;
    sb[i2] = (i2 < NB) ? bucketCursor[i2] : 0;
    deg[tid] = 0;
    __syncthreads();
    for (int off = 1; off < NBMAX; off <<= 1) {  // Hillis-Steele, 2 slots/thread
        int a = (i1 >= off) ? sb[i1 - off] : 0;
        int c = (i2 >= off) ? sb[i2 - off] : 0;
        __syncthreads();
        sb[i1] += a;
        sb[i2] += c;
        __syncthreads();
    }
    int base = (b == 0) ? 0 : sb[b - 1];
    int size = sb[b] - base;
    if (b == 0 && tid == 0) rp[N] = E;
    const unsigned* st = staging + (size_t)b * CAP;
    for (int i = tid; i < size; i += 256) atomicAdd(&deg[st[i] & 255u], 1);
    __syncthreads();
    int g = b * 256 + tid;
    int d = deg[tid];
    if (g < N) dinv[g] = rsqrtf((float)(d + 1));  // +1 self-loop
    scn[tid] = d;
    __syncthreads();
    for (int off = 1; off < 256; off <<= 1) {
        int t = (tid >= off) ? scn[tid - off] : 0;
        __syncthreads();
        scn[tid] += t;
        __syncthreads();
    }
    int excl = scn[tid] - d;
    if (g < N) rp[g] = base + excl;
    cur[tid] = excl;
    __syncthreads();
    for (int i = tid; i < size; i += 256) {
        unsigned pk = st[i];
        int pos = atomicAdd(&cur[pk & 255u], 1);
        col[base + pos] = (int)(pk >> 8);
    }
}

// h1[row] = bf16( (X[row] @ W1) * dinv[row] ); 128-row tile, thread = 4 rows x 8 cols.
__global__ __launch_bounds__(256) void gemm1(const float* __restrict__ X,
                                             const float* __restrict__ W,
                                             const float* __restrict__ dinv,
                                             unsigned short* __restrict__ Hout, int N) {
    constexpr int XS = 65;
    __shared__ float Xs[128 * XS];
    __shared__ float Ws[64 * 64];
    int tid = threadIdx.x;
    int rowBase = blockIdx.x * 128;
    const float4* Wv = (const float4*)W;
    float4* Wsv = (float4*)Ws;
    for (int i = tid; i < 64 * 64 / 4; i += 256) Wsv[i] = Wv[i];
    const float4* Xv = (const float4*)X;
    for (int v = tid; v < 128 * 16; v += 256) {
        int r = v >> 4, j = v & 15;
        int gr = rowBase + r;
        float4 t = make_float4(0.f, 0.f, 0.f, 0.f);
        if (gr < N) t = Xv[(size_t)gr * 16 + j];
        int b = r * XS + j * 4;
        Xs[b] = t.x;
        Xs[b + 1] = t.y;
        Xs[b + 2] = t.z;
        Xs[b + 3] = t.w;
    }
    __syncthreads();
    int cg = tid % 8, rg = tid / 8;
    int c0 = cg * 8, r0 = rg * 4;
    float acc[4][8];
#pragma unroll
    for (int i = 0; i < 4; ++i)
#pragma unroll
        for (int j = 0; j < 8; ++j) acc[i][j] = 0.f;
#pragma unroll 8
    for (int k = 0; k < 64; ++k) {
        float4 w0 = *(const float4*)&Ws[k * 64 + c0];
        float4 w1 = *(const float4*)&Ws[k * 64 + c0 + 4];
        float xr[4];
#pragma unroll
        for (int i = 0; i < 4; ++i) xr[i] = Xs[(r0 + i) * XS + k];
#pragma unroll
        for (int i = 0; i < 4; ++i) {
            acc[i][0] = fmaf(xr[i], w0.x, acc[i][0]);
            acc[i][1] = fmaf(xr[i], w0.y, acc[i][1]);
            acc[i][2] = fmaf(xr[i], w0.z, acc[i][2]);
            acc[i][3] = fmaf(xr[i], w0.w, acc[i][3]);
            acc[i][4] = fmaf(xr[i], w1.x, acc[i][4]);
            acc[i][5] = fmaf(xr[i], w1.y, acc[i][5]);
            acc[i][6] = fmaf(xr[i], w1.z, acc[i][6]);
            acc[i][7] = fmaf(xr[i], w1.w, acc[i][7]);
        }
    }
#pragma unroll
    for (int i = 0; i < 4; ++i) {
        int row = rowBase + r0 + i;
        if (row >= N) continue;
        float dn = dinv[row];
        unsigned pk[4];
#pragma unroll
        for (int j = 0; j < 4; ++j) {
            unsigned lo = f2bf(acc[i][2 * j] * dn);
            unsigned hi = f2bf(acc[i][2 * j + 1] * dn);
            pk[j] = lo | (hi << 16);
        }
        *(uint4*)(Hout + (size_t)row * 64 + c0) = make_uint4(pk[0], pk[1], pk[2], pk[3]);
    }
}

// Fused layer-1 aggregate + layer-2 linear. 64 nodes/block, 32 groups of 8
// threads; groups grab nodes dynamically from an LDS counter (tail balancing).
// Phase B: 256 threads = 64 nodes x 4 col-groups of 8 channels.
__global__ __launch_bounds__(256) void agg1_gemm2(
    const uint4* __restrict__ hs1, const float* __restrict__ dinv, const int* __restrict__ rp,
    const int* __restrict__ col, const float* __restrict__ b1, const float* __restrict__ W2,
    unsigned short* __restrict__ h2, int N) {
    constexpr int RS = 68;
    constexpr int NPB = 64;
    __shared__ float rows[NPB * RS];  // 17408 B
    __shared__ float Ws2[64 * 32];    // 8192 B
    __shared__ int ctr;
    int tid = threadIdx.x;
    const float4* W2v = (const float4*)W2;
    float4* Ws2v = (float4*)Ws2;
    for (int i = tid; i < 64 * 32 / 4; i += 256) Ws2v[i] = W2v[i];
    if (tid == 0) ctr = 32;
    __syncthreads();

    int lane = tid & 63;
    int gbase = lane & ~7;  // shfl source lane (group leader)
    int q = tid & 7;
    int cur = tid >> 3;  // initial node slot (0..31)
    int blockBase = blockIdx.x * NPB;
    while (cur < NPB) {
        int node = blockBase + cur;
        if (node < N) {
            float dn = dinv[node];
            float acc[8];
            uint4 u = hs1[(size_t)node * 8 + q];  // self-loop (pre-scaled)
            acc[0] = bflo(u.x); acc[1] = bfhi(u.x);
            acc[2] = bflo(u.y); acc[3] = bfhi(u.y);
            acc[4] = bflo(u.z); acc[5] = bfhi(u.z);
            acc[6] = bflo(u.w); acc[7] = bfhi(u.w);
            int e0 = rp[node], e1 = rp[node + 1];
            int e = e0;
#define ACC8(U)                               \
    acc[0] += bflo(U.x); acc[1] += bfhi(U.x); \
    acc[2] += bflo(U.y); acc[3] += bfhi(U.y); \
    acc[4] += bflo(U.z); acc[5] += bfhi(U.z); \
    acc[6] += bflo(U.w); acc[7] += bfhi(U.w);
            for (; e + 4 <= e1; e += 4) {
                int s0 = col[e], s1 = col[e + 1], s2 = col[e + 2], s3 = col[e + 3];
                uint4 u0 = hs1[(size_t)s0 * 8 + q];
                uint4 u1 = hs1[(size_t)s1 * 8 + q];
                uint4 u2 = hs1[(size_t)s2 * 8 + q];
                uint4 u3 = hs1[(size_t)s3 * 8 + q];
                ACC8(u0) ACC8(u1) ACC8(u2) ACC8(u3)
            }
            for (; e < e1; ++e) {
                uint4 uu = hs1[(size_t)col[e] * 8 + q];
                ACC8(uu)
            }
#undef ACC8
            const float4* bv = (const float4*)b1;
            float4 bb0 = bv[q * 2], bb1 = bv[q * 2 + 1];
            float* myrow = &rows[cur * RS + q * 8];
            *(float4*)myrow =
                make_float4(fmaxf(fmaf(acc[0], dn, bb0.x), 0.f), fmaxf(fmaf(acc[1], dn, bb0.y), 0.f),
                            fmaxf(fmaf(acc[2], dn, bb0.z), 0.f), fmaxf(fmaf(acc[3], dn, bb0.w), 0.f));
            *(float4*)(myrow + 4) =
                make_float4(fmaxf(fmaf(acc[4], dn, bb1.x), 0.f), fmaxf(fmaf(acc[5], dn, bb1.y), 0.f),
                            fmaxf(fmaf(acc[6], dn, bb1.z), 0.f), fmaxf(fmaf(acc[7], dn, bb1.w), 0.f));
        }
        int nxt = 0;
        if (q == 0) nxt = atomicAdd(&ctr, 1);  // LDS atomic
        nxt = __shfl(nxt, gbase, 64);
        cur = nxt;
    }
    __syncthreads();

    // Phase B: h2[node] = bf16( (rows[node] @ W2) * dinv[node] )
    int r = tid >> 2;
    int c0 = (tid & 3) * 8;
    int node = blockBase + r;
    if (node >= N) return;
    float dn = dinv[node];
    float acc2[8];
#pragma unroll
    for (int j = 0; j < 8; ++j) acc2[j] = 0.f;
    const float* row = &rows[r * RS];
#pragma unroll
    for (int k4 = 0; k4 < 16; ++k4) {
        float4 xq = *(const float4*)&row[k4 * 4];
#pragma unroll
        for (int kk = 0; kk < 4; ++kk) {
            float xv = (&xq.x)[kk];
            float4 wa = *(const float4*)&Ws2[(k4 * 4 + kk) * 32 + c0];
            float4 wb = *(const float4*)&Ws2[(k4 * 4 + kk) * 32 + c0 + 4];
            acc2[0] = fmaf(xv, wa.x, acc2[0]);
            acc2[1] = fmaf(xv, wa.y, acc2[1]);
            acc2[2] = fmaf(xv, wa.z, acc2[2]);
            acc2[3] = fmaf(xv, wa.w, acc2[3]);
            acc2[4] = fmaf(xv, wb.x, acc2[4]);
            acc2[5] = fmaf(xv, wb.y, acc2[5]);
            acc2[6] = fmaf(xv, wb.z, acc2[6]);
            acc2[7] = fmaf(xv, wb.w, acc2[7]);
        }
    }
    unsigned pk[4];
#pragma unroll
    for (int j = 0; j < 4; ++j) {
        unsigned lo = f2bf(acc2[2 * j] * dn);
        unsigned hi = f2bf(acc2[2 * j + 1] * dn);
        pk[j] = lo | (hi << 16);
    }
    *(uint4*)(h2 + (size_t)node * 32 + c0) = make_uint4(pk[0], pk[1], pk[2], pk[3]);
}

// Layer-2 aggregate: bf16 rows (32 ch), groups of 4 threads, 128 nodes/block
// with dynamic grabbing (64 groups, avg 2 nodes each).
__global__ __launch_bounds__(256) void agg2(const uint4* __restrict__ hs2,
                                            const float* __restrict__ dinv,
                                            const int* __restrict__ rp,
                                            const int* __restrict__ col,
                                            const float* __restrict__ bias,
                                            float* __restrict__ out, int N) {
    constexpr int NPB = 128;
    __shared__ int ctr;
    int tid = threadIdx.x;
    if (tid == 0) ctr = 64;
    __syncthreads();
    int lane = tid & 63;
    int gbase = lane & ~3;
    int q = tid & 3;
    int cur = tid >> 2;  // 0..63
    int blockBase = blockIdx.x * NPB;
    while (cur < NPB) {
        int node = blockBase + cur;
        if (node < N) {
            float acc[8];
            uint4 u = hs2[(size_t)node * 4 + q];  // self-loop (pre-scaled)
            acc[0] = bflo(u.x); acc[1] = bfhi(u.x);
            acc[2] = bflo(u.y); acc[3] = bfhi(u.y);
            acc[4] = bflo(u.z); acc[5] = bfhi(u.z);
            acc[6] = bflo(u.w); acc[7] = bfhi(u.w);
            int e0 = rp[node], e1 = rp[node + 1];
            int e = e0;
#define ACC8(U)                               \
    acc[0] += bflo(U.x); acc[1] += bfhi(U.x); \
    acc[2] += bflo(U.y); acc[3] += bfhi(U.y); \
    acc[4] += bflo(U.z); acc[5] += bfhi(U.z); \
    acc[6] += bflo(U.w); acc[7] += bfhi(U.w);
            for (; e + 4 <= e1; e += 4) {
                int s0 = col[e], s1 = col[e + 1], s2 = col[e + 2], s3 = col[e + 3];
                uint4 u0 = hs2[(size_t)s0 * 4 + q];
                uint4 u1 = hs2[(size_t)s1 * 4 + q];
                uint4 u2 = hs2[(size_t)s2 * 4 + q];
                uint4 u3 = hs2[(size_t)s3 * 4 + q];
                ACC8(u0) ACC8(u1) ACC8(u2) ACC8(u3)
            }
            for (; e < e1; ++e) {
                uint4 uu = hs2[(size_t)col[e] * 4 + q];
                ACC8(uu)
            }
#undef ACC8
            float dn = dinv[node];
            const float4* bv = (const float4*)bias;
            float4 b0 = bv[q * 2], b1 = bv[q * 2 + 1];
            float4* ov = (float4*)(out + (size_t)node * 32 + q * 8);
            ov[0] = make_float4(fmaf(acc[0], dn, b0.x), fmaf(acc[1], dn, b0.y),
                                fmaf(acc[2], dn, b0.z), fmaf(acc[3], dn, b0.w));
            ov[1] = make_float4(fmaf(acc[4], dn, b1.x), fmaf(acc[5], dn, b1.y),
                                fmaf(acc[6], dn, b1.z), fmaf(acc[7], dn, b1.w));
        }
        int nxt = 0;
        if (q == 0) nxt = atomicAdd(&ctr, 1);  // LDS atomic
        nxt = __shfl(nxt, gbase, 64);
        cur = nxt;
    }
}

extern "C" void kernel_launch(void* const* d_in, const int* in_sizes, int n_in,
                              void* d_out, int out_size, void* d_ws, size_t ws_size,
                              hipStream_t stream) {
    const float* x = (const float*)d_in[0];
    const int* ei = (const int*)d_in[1];  // int64 in reference -> int32 from harness
    const float* W1 = (const float*)d_in[3];
    const float* b1 = (const float*)d_in[4];
    const float* W2 = (const float*)d_in[5];
    const float* b2 = (const float*)d_in[6];

    constexpr int CIN = 64, CHID = 64;
    const int N = in_sizes[0] / CIN;
    const int E = in_sizes[1] / 2;
    const int* src = ei;
    const int* dst = ei + E;
    const int NB = (N + 255) >> 8;  // must be <= NBMAX

    char* p = (char*)d_ws;
    auto carve = [&](size_t bytes) -> void* {
        void* q = (void*)p;
        p += (bytes + 255) & ~(size_t)255;
        return q;
    };
    int* bucketCursor = (int*)carve((size_t)NB * 4);
    int* rp = (int*)carve((size_t)(N + 1) * 4);
    int* col = (int*)carve((size_t)E * 4);
    float* dinv = (float*)carve((size_t)N * 4);
    unsigned* staging = (unsigned*)carve((size_t)NB * CAP * 4);         // 12.8 MB
    unsigned short* h1 = (unsigned short*)carve((size_t)N * CHID * 2);  // bf16
    unsigned short* h2 = (unsigned short*)staging;  // staging dead after p2_csr

    hipMemsetAsync(bucketCursor, 0, (size_t)NB * 4, stream);
    p1_bin<<<(E + 4095) / 4096, 256, 0, stream>>>(src, dst, bucketCursor, staging, E, NB);
    p2_csr<<<NB, 256, 0, stream>>>(staging, bucketCursor, rp, col, dinv, N, E, NB);

    gemm1<<<(N + 127) / 128, 256, 0, stream>>>(x, W1, dinv, h1, N);
    agg1_gemm2<<<(N + 63) / 64, 256, 0, stream>>>((const uint4*)h1, dinv, rp, col, b1, W2, h2, N);
    agg2<<<(N + 127) / 128, 256, 0, stream>>>((const uint4*)h2, dinv, rp, col, b2, (float*)d_out,
                                              N);
}

// Round 8
// 212.612 us; speedup vs baseline: 1.0359x; 1.0359x over previous
//
#include <hip/hip_runtime.h>

// GCN 2-layer encoder on gfx950.
// R8: revert R7's dynamic balancing (LDS-ctr serialization + occupancy loss).
// Instead: split each node's edge walk across 2 wave subgroups, combine with
// __shfl_xor (no LDS, no atomics). Walk latency ~halves, MLP doubles.
// Pipeline: memset(1.5KB) -> p1_bin -> p2_csr -> gemm1(bf16 h1)
//           -> agg1_gemm2(bf16 h2) -> agg2 -> d_out (fp32).

constexpr int CAP = 8192;   // per-bucket staging cap; E/NB ~ 4092
constexpr int NBMAX = 512;  // NB = 391 for N = 100000 (must be <= 512)

__device__ inline unsigned short f2bf(float f) {  // RNE f32->bf16 (finite inputs)
    unsigned u = __float_as_uint(f);
    u += 0x7fff + ((u >> 16) & 1);
    return (unsigned short)(u >> 16);
}
__device__ inline float bflo(unsigned u) { return __uint_as_float(u << 16); }
__device__ inline float bfhi(unsigned u) { return __uint_as_float(u & 0xffff0000u); }

__global__ __launch_bounds__(256) void p1_bin(const int* __restrict__ src,
                                              const int* __restrict__ dst,
                                              int* __restrict__ bucketCursor,
                                              unsigned* __restrict__ staging, int E, int NB) {
    __shared__ int cnt[NBMAX];
    __shared__ int cur[NBMAX];
    int tid = threadIdx.x;
    for (int i = tid; i < NB; i += 256) cnt[i] = 0;
    __syncthreads();
    int e0 = blockIdx.x * 4096;
#pragma unroll
    for (int k = 0; k < 16; ++k) {
        int e = e0 + k * 256 + tid;
        if (e < E) atomicAdd(&cnt[dst[e] >> 8], 1);  // LDS atomic
    }
    __syncthreads();
    for (int i = tid; i < NB; i += 256) {
        int c = cnt[i];
        cur[i] = c ? atomicAdd(&bucketCursor[i], c) : 0;  // 1 global atomic/(block,bucket)
    }
    __syncthreads();
#pragma unroll
    for (int k = 0; k < 16; ++k) {
        int e = e0 + k * 256 + tid;
        if (e < E) {
            int d = dst[e];
            int b = d >> 8;
            int slot = atomicAdd(&cur[b], 1);  // LDS atomic; runs contiguous per bucket
            staging[(size_t)b * CAP + slot] = ((unsigned)src[e] << 8) | (unsigned)(d & 255);
        }
    }
}

// One block per bucket. In-block scan of all bucket counts (no separate
// scan dispatch); then local deg/scan/cursor in LDS; emit rp, col, dinv.
__global__ __launch_bounds__(256) void p2_csr(const unsigned* __restrict__ staging,
                                              const int* __restrict__ bucketCursor,
                                              int* __restrict__ rp, int* __restrict__ col,
                                              float* __restrict__ dinv, int N, int E, int NB) {
    __shared__ int sb[NBMAX];
    __shared__ int deg[256];
    __shared__ int scn[256];
    __shared__ int cur[256];
    int b = blockIdx.x;
    int tid = threadIdx.x;
    int i1 = tid, i2 = tid + 256;
    sb[i1] = (i1 < NB) ? bucketCursor[i1] : 0;
    sb[i2] = (i2 < NB) ? bucketCursor[i2] : 0;
    deg[tid] = 0;
    __syncthreads();
    for (int off = 1; off < NBMAX; off <<= 1) {  // Hillis-Steele, 2 slots/thread
        int a = (i1 >= off) ? sb[i1 - off] : 0;
        int c = (i2 >= off) ? sb[i2 - off] : 0;
        __syncthreads();
        sb[i1] += a;
        sb[i2] += c;
        __syncthreads();
    }
    int base = (b == 0) ? 0 : sb[b - 1];
    int size = sb[b] - base;
    if (b == 0 && tid == 0) rp[N] = E;
    const unsigned* st = staging + (size_t)b * CAP;
    for (int i = tid; i < size; i += 256) atomicAdd(&deg[st[i] & 255u], 1);
    __syncthreads();
    int g = b * 256 + tid;
    int d = deg[tid];
    if (g < N) dinv[g] = rsqrtf((float)(d + 1));  // +1 self-loop
    scn[tid] = d;
    __syncthreads();
    for (int off = 1; off < 256; off <<= 1) {
        int t = (tid >= off) ? scn[tid - off] : 0;
        __syncthreads();
        scn[tid] += t;
        __syncthreads();
    }
    int excl = scn[tid] - d;
    if (g < N) rp[g] = base + excl;
    cur[tid] = excl;
    __syncthreads();
    for (int i = tid; i < size; i += 256) {
        unsigned pk = st[i];
        int pos = atomicAdd(&cur[pk & 255u], 1);
        col[base + pos] = (int)(pk >> 8);
    }
}

// h1[row] = bf16( (X[row] @ W1) * dinv[row] ); 128-row tile, thread = 4 rows x 8 cols.
__global__ __launch_bounds__(256) void gemm1(const float* __restrict__ X,
                                             const float* __restrict__ W,
                                             const float* __restrict__ dinv,
                                             unsigned short* __restrict__ Hout, int N) {
    constexpr int XS = 65;
    __shared__ float Xs[128 * XS];
    __shared__ float Ws[64 * 64];
    int tid = threadIdx.x;
    int rowBase = blockIdx.x * 128;
    const float4* Wv = (const float4*)W;
    float4* Wsv = (float4*)Ws;
    for (int i = tid; i < 64 * 64 / 4; i += 256) Wsv[i] = Wv[i];
    const float4* Xv = (const float4*)X;
    for (int v = tid; v < 128 * 16; v += 256) {
        int r = v >> 4, j = v & 15;
        int gr = rowBase + r;
        float4 t = make_float4(0.f, 0.f, 0.f, 0.f);
        if (gr < N) t = Xv[(size_t)gr * 16 + j];
        int b = r * XS + j * 4;
        Xs[b] = t.x;
        Xs[b + 1] = t.y;
        Xs[b + 2] = t.z;
        Xs[b + 3] = t.w;
    }
    __syncthreads();
    int cg = tid % 8, rg = tid / 8;
    int c0 = cg * 8, r0 = rg * 4;
    float acc[4][8];
#pragma unroll
    for (int i = 0; i < 4; ++i)
#pragma unroll
        for (int j = 0; j < 8; ++j) acc[i][j] = 0.f;
#pragma unroll 8
    for (int k = 0; k < 64; ++k) {
        float4 w0 = *(const float4*)&Ws[k * 64 + c0];
        float4 w1 = *(const float4*)&Ws[k * 64 + c0 + 4];
        float xr[4];
#pragma unroll
        for (int i = 0; i < 4; ++i) xr[i] = Xs[(r0 + i) * XS + k];
#pragma unroll
        for (int i = 0; i < 4; ++i) {
            acc[i][0] = fmaf(xr[i], w0.x, acc[i][0]);
            acc[i][1] = fmaf(xr[i], w0.y, acc[i][1]);
            acc[i][2] = fmaf(xr[i], w0.z, acc[i][2]);
            acc[i][3] = fmaf(xr[i], w0.w, acc[i][3]);
            acc[i][4] = fmaf(xr[i], w1.x, acc[i][4]);
            acc[i][5] = fmaf(xr[i], w1.y, acc[i][5]);
            acc[i][6] = fmaf(xr[i], w1.z, acc[i][6]);
            acc[i][7] = fmaf(xr[i], w1.w, acc[i][7]);
        }
    }
#pragma unroll
    for (int i = 0; i < 4; ++i) {
        int row = rowBase + r0 + i;
        if (row >= N) continue;
        float dn = dinv[row];
        unsigned pk[4];
#pragma unroll
        for (int j = 0; j < 4; ++j) {
            unsigned lo = f2bf(acc[i][2 * j] * dn);
            unsigned hi = f2bf(acc[i][2 * j + 1] * dn);
            pk[j] = lo | (hi << 16);
        }
        *(uint4*)(Hout + (size_t)row * 64 + c0) = make_uint4(pk[0], pk[1], pk[2], pk[3]);
    }
}

#define WALK8(HS, STRIDE)                                                   \
    {                                                                       \
        int e = es;                                                         \
        for (; e + 4 <= ee; e += 4) {                                       \
            int s0 = col[e], s1 = col[e + 1], s2 = col[e + 2],              \
                s3 = col[e + 3];                                            \
            uint4 u0 = HS[(size_t)s0 * STRIDE + q];                         \
            uint4 u1 = HS[(size_t)s1 * STRIDE + q];                         \
            uint4 u2 = HS[(size_t)s2 * STRIDE + q];                         \
            uint4 u3 = HS[(size_t)s3 * STRIDE + q];                         \
            ACC8(u0) ACC8(u1) ACC8(u2) ACC8(u3)                             \
        }                                                                   \
        for (; e < ee; ++e) {                                               \
            uint4 uu = HS[(size_t)col[e] * STRIDE + q];                     \
            ACC8(uu)                                                        \
        }                                                                   \
    }
#define ACC8(U)                               \
    acc[0] += bflo(U.x); acc[1] += bfhi(U.x); \
    acc[2] += bflo(U.y); acc[3] += bfhi(U.y); \
    acc[4] += bflo(U.z); acc[5] += bfhi(U.z); \
    acc[6] += bflo(U.w); acc[7] += bfhi(U.w);

// Fused layer-1 aggregate + layer-2 linear. 16 nodes/block, 16 threads/node =
// 2 edge-subgroups x 8 lanes; subgroup walks half the edge list (full 128B row
// gather per subgroup), partials combined via shfl_xor(8). Phase B: 16
// threads/node x 2 out-ch, conflict-free float2 W2 reads.
__global__ __launch_bounds__(256) void agg1_gemm2(
    const uint4* __restrict__ hs1, const float* __restrict__ dinv, const int* __restrict__ rp,
    const int* __restrict__ col, const float* __restrict__ b1, const float* __restrict__ W2,
    unsigned short* __restrict__ h2, int N) {
    constexpr int RS = 68;
    constexpr int NPB = 16;
    __shared__ float rows[NPB * RS];  // 4352 B
    __shared__ float Ws2[64 * 32];    // 8192 B
    int tid = threadIdx.x;
    const float4* W2v = (const float4*)W2;
    float4* Ws2v = (float4*)Ws2;
    for (int i = tid; i < 64 * 32 / 4; i += 256) Ws2v[i] = W2v[i];

    int r = tid >> 4;        // node slot 0..15
    int t16 = tid & 15;
    int sg = t16 >> 3;       // edge-half
    int q = t16 & 7;         // uint4 quad within row
    int node = blockIdx.x * NPB + r;
    float dn = 0.f;
    float acc[8];
#pragma unroll
    for (int j = 0; j < 8; ++j) acc[j] = 0.f;
    if (node < N) {
        dn = dinv[node];
        if (sg == 0) {
            uint4 u = hs1[(size_t)node * 8 + q];  // self-loop (pre-scaled)
            acc[0] = bflo(u.x); acc[1] = bfhi(u.x);
            acc[2] = bflo(u.y); acc[3] = bfhi(u.y);
            acc[4] = bflo(u.z); acc[5] = bfhi(u.z);
            acc[6] = bflo(u.w); acc[7] = bfhi(u.w);
        }
        int e0 = rp[node], e1 = rp[node + 1];
        int mid = (e0 + e1 + 1) >> 1;
        int es = sg ? mid : e0;
        int ee = sg ? e1 : mid;
        WALK8(hs1, 8)
    }
#pragma unroll
    for (int j = 0; j < 8; ++j) acc[j] += __shfl_xor(acc[j], 8, 64);
    if (node < N && sg == 0) {
        const float4* bv = (const float4*)b1;
        float4 bb0 = bv[q * 2], bb1 = bv[q * 2 + 1];
        float* myrow = &rows[r * RS + q * 8];
        *(float4*)myrow =
            make_float4(fmaxf(fmaf(acc[0], dn, bb0.x), 0.f), fmaxf(fmaf(acc[1], dn, bb0.y), 0.f),
                        fmaxf(fmaf(acc[2], dn, bb0.z), 0.f), fmaxf(fmaf(acc[3], dn, bb0.w), 0.f));
        *(float4*)(myrow + 4) =
            make_float4(fmaxf(fmaf(acc[4], dn, bb1.x), 0.f), fmaxf(fmaf(acc[5], dn, bb1.y), 0.f),
                        fmaxf(fmaf(acc[6], dn, bb1.z), 0.f), fmaxf(fmaf(acc[7], dn, bb1.w), 0.f));
    }
    __syncthreads();

    // Phase B: h2[node, c0:c0+2] = bf16( (rows[node] @ W2[:, c0:c0+2]) * dn )
    if (node >= N) return;
    int c0 = t16 * 2;
    float a0 = 0.f, a1 = 0.f;
    const float* row = &rows[r * RS];
#pragma unroll
    for (int k4 = 0; k4 < 16; ++k4) {
        float4 xq = *(const float4*)&row[k4 * 4];
#pragma unroll
        for (int kk = 0; kk < 4; ++kk) {
            float xv = (&xq.x)[kk];
            float2 w = *(const float2*)&Ws2[(k4 * 4 + kk) * 32 + c0];
            a0 = fmaf(xv, w.x, a0);
            a1 = fmaf(xv, w.y, a1);
        }
    }
    unsigned pk = (unsigned)f2bf(a0 * dn) | ((unsigned)f2bf(a1 * dn) << 16);
    *(unsigned*)(h2 + (size_t)node * 32 + c0) = pk;
}

// Layer-2 aggregate: bf16 rows (32 ch). 8 threads/node = 2 edge-subgroups x 4
// lanes (64B row gather per subgroup); shfl_xor(4) combine. No LDS, no sync.
__global__ __launch_bounds__(256) void agg2(const uint4* __restrict__ hs2,
                                            const float* __restrict__ dinv,
                                            const int* __restrict__ rp,
                                            const int* __restrict__ col,
                                            const float* __restrict__ bias,
                                            float* __restrict__ out, int N) {
    int tid = blockIdx.x * blockDim.x + threadIdx.x;
    int node = tid >> 3;
    int t8 = tid & 7;
    int sg = t8 >> 2, q = t8 & 3;
    if (node >= N) return;
    float acc[8];
#pragma unroll
    for (int j = 0; j < 8; ++j) acc[j] = 0.f;
    if (sg == 0) {
        uint4 u = hs2[(size_t)node * 4 + q];  // self-loop (pre-scaled)
        acc[0] = bflo(u.x); acc[1] = bfhi(u.x);
        acc[2] = bflo(u.y); acc[3] = bfhi(u.y);
        acc[4] = bflo(u.z); acc[5] = bfhi(u.z);
        acc[6] = bflo(u.w); acc[7] = bfhi(u.w);
    }
    int e0 = rp[node], e1 = rp[node + 1];
    int mid = (e0 + e1 + 1) >> 1;
    int es = sg ? mid : e0;
    int ee = sg ? e1 : mid;
    WALK8(hs2, 4)
#pragma unroll
    for (int j = 0; j < 8; ++j) acc[j] += __shfl_xor(acc[j], 4, 64);
    if (sg) return;
    float dn = dinv[node];
    const float4* bv = (const float4*)bias;
    float4 b0 = bv[q * 2], b1 = bv[q * 2 + 1];
    float4* ov = (float4*)(out + (size_t)node * 32 + q * 8);
    ov[0] = make_float4(fmaf(acc[0], dn, b0.x), fmaf(acc[1], dn, b0.y), fmaf(acc[2], dn, b0.z),
                        fmaf(acc[3], dn, b0.w));
    ov[1] = make_float4(fmaf(acc[4], dn, b1.x), fmaf(acc[5], dn, b1.y), fmaf(acc[6], dn, b1.z),
                        fmaf(acc[7], dn, b1.w));
}

extern "C" void kernel_launch(void* const* d_in, const int* in_sizes, int n_in,
                              void* d_out, int out_size, void* d_ws, size_t ws_size,
                              hipStream_t stream) {
    const float* x = (const float*)d_in[0];
    const int* ei = (const int*)d_in[1];  // int64 in reference -> int32 from harness
    const float* W1 = (const float*)d_in[3];
    const float* b1 = (const float*)d_in[4];
    const float* W2 = (const float*)d_in[5];
    const float* b2 = (const float*)d_in[6];

    constexpr int CIN = 64, CHID = 64;
    const int N = in_sizes[0] / CIN;
    const int E = in_sizes[1] / 2;
    const int* src = ei;
    const int* dst = ei + E;
    const int NB = (N + 255) >> 8;  // must be <= NBMAX

    char* p = (char*)d_ws;
    auto carve = [&](size_t bytes) -> void* {
        void* q = (void*)p;
        p += (bytes + 255) & ~(size_t)255;
        return q;
    };
    int* bucketCursor = (int*)carve((size_t)NB * 4);
    int* rp = (int*)carve((size_t)(N + 1) * 4);
    int* col = (int*)carve((size_t)E * 4);
    float* dinv = (float*)carve((size_t)N * 4);
    unsigned* staging = (unsigned*)carve((size_t)NB * CAP * 4);         // 12.8 MB
    unsigned short* h1 = (unsigned short*)carve((size_t)N * CHID * 2);  // bf16
    unsigned short* h2 = (unsigned short*)staging;  // staging dead after p2_csr

    hipMemsetAsync(bucketCursor, 0, (size_t)NB * 4, stream);
    p1_bin<<<(E + 4095) / 4096, 256, 0, stream>>>(src, dst, bucketCursor, staging, E, NB);
    p2_csr<<<NB, 256, 0, stream>>>(staging, bucketCursor, rp, col, dinv, N, E, NB);

    gemm1<<<(N + 127) / 128, 256, 0, stream>>>(x, W1, dinv, h1, N);
    agg1_gemm2<<<(N + 15) / 16, 256, 0, stream>>>((const uint4*)h1, dinv, rp, col, b1, W2, h2, N);
    agg2<<<((size_t)N * 8 + 255) / 256, 256, 0, stream>>>((const uint4*)h2, dinv, rp, col, b2,
                                                          (float*)d_out, N);
}